// Round 8
// baseline (180.554 us; speedup 1.0000x reference)
//
#include <hip/hip_runtime.h>
#include <hip/hip_bf16.h>

// Problem: B=8, T=2048, C=1024, HS=64. fp32 in/out.
// d_in: x[8,2048,1024], Wq[1024,64], Wk[1024,64], Wv[1024,64]
// d_out: [8,2048,64] fp32
// Workspace: q bf16 [16384][64] (pre-scaled log2e/32), k bf16 [16384][64],
//            vT bf16 [8][64][2048], Wt bf16 [192][1024]  (~6.4 MB)

#define T_SEQ 2048
#define C_DIM 1024
#define HS 64
#define BT 16384

typedef short s8v __attribute__((ext_vector_type(8)));   // 8 bf16
typedef float f4v __attribute__((ext_vector_type(4)));   // MFMA C/D

__device__ inline unsigned short f2bf(float f) {
  union { float f; unsigned u; } a; a.f = f;
  unsigned r = a.u + 0x7fffu + ((a.u >> 16) & 1u);  // RNE
  return (unsigned short)(r >> 16);
}

// HW-packed f32x2 -> bf16x2 (v_cvt_pk_bf16_f32), 4 ops per 8 elements
__device__ inline s8v cvt8(float4 v0, float4 v1) {
  union { __hip_bfloat162 h; unsigned u; } c0, c1, c2, c3;
  c0.h = __float22bfloat162_rn(make_float2(v0.x, v0.y));
  c1.h = __float22bfloat162_rn(make_float2(v0.z, v0.w));
  c2.h = __float22bfloat162_rn(make_float2(v1.x, v1.y));
  c3.h = __float22bfloat162_rn(make_float2(v1.z, v1.w));
  union { unsigned u[4]; s8v v; } r;
  r.u[0] = c0.u; r.u[1] = c1.u; r.u[2] = c2.u; r.u[3] = c3.u;
  return r.v;
}

// async global->LDS, 16 B/lane. LDS base MUST be wave-uniform (SGPR).
__device__ inline void gl_lds16(const void* g, unsigned char* lds_base,
                                unsigned uniform_byte_off) {
  __builtin_amdgcn_global_load_lds(
      (const __attribute__((address_space(1))) unsigned int*)g,
      (__attribute__((address_space(3))) unsigned int*)(lds_base + uniform_byte_off),
      16, 0, 0);
}

// ------------- Kernel 0: W transpose via LDS (coalesced both ways) -------
__global__ __launch_bounds__(256) void wt_kernel(
    const float* __restrict__ Wq, const float* __restrict__ Wk,
    const float* __restrict__ Wv, unsigned short* __restrict__ wt) {
  __shared__ float tile[64][65];
  const int bid = blockIdx.x;
  const int mat = bid >> 4, kt = bid & 15;
  const float* W = (mat == 0) ? Wq : ((mat == 1) ? Wk : Wv);
  const int t = threadIdx.x;
  const int n = t & 63, kr = t >> 6;
#pragma unroll
  for (int j = 0; j < 16; ++j) {
    const int kl = j * 4 + kr;
    tile[kl][n] = W[(kt * 64 + kl) * HS + n];
  }
  __syncthreads();
  const int n2 = t >> 2, kp = t & 3;
  unsigned int* orow =
      (unsigned int*)(wt + (size_t)(mat * 64 + n2) * C_DIM + kt * 64);
#pragma unroll
  for (int i = 0; i < 8; ++i) {
    const int k0 = kp * 16 + i * 2;
    unsigned int lo = f2bf(tile[k0][n2]);
    unsigned int hi = f2bf(tile[k0 + 1][n2]);
    orow[kp * 8 + i] = lo | (hi << 16);
  }
}

// ------------- Kernel A: QKV projection, async LDS double-buffer ---------
// 512 blocks x 256 threads. M-tile 32; N = 192 (q|k|v); BK = 64.
// 12 MFMA per barrier per wave, 16 barriers. LDS 64 KB -> 2 blocks/CU ->
// 4 waves/SIMD, so (256,4) lets VGPRs go to 128 without occupancy loss.
__global__ __launch_bounds__(256, 4) void qkv_kernel(
    const float* __restrict__ x, const unsigned short* __restrict__ wt,
    unsigned short* __restrict__ qws, unsigned short* __restrict__ kws,
    unsigned short* __restrict__ vtws) {
  __shared__ unsigned char abuf[2][8192];    // 32 rows x 64 fp32 (16 parts)
  __shared__ unsigned char bbuf[2][24576];   // 192 rows x 64 bf16 (8 parts)

  const int tid  = threadIdx.x;
  const int wv   = tid >> 6;
  const int lane = tid & 63;
  const int m    = lane & 15;
  const int quad = lane >> 4;
  const int row0 = blockIdx.x * 32;
  const int mh   = wv >> 1;
  const int ng   = (wv & 1) * 6;

  f4v acc[6];
#pragma unroll
  for (int j = 0; j < 6; ++j) acc[j] = (f4v)0.0f;

  // wave-uniform LDS slot base (bytes); HW adds lane*16
  const unsigned au = (unsigned)__builtin_amdgcn_readfirstlane(tid & 192) << 4;

  // staging slot -> global mapping (XOR-swizzled 16B parts within rows)
  const float* agp[2];
#pragma unroll
  for (int j = 0; j < 2; ++j) {
    const int s = tid + j * 256;
    const int r = s >> 4, p = (s & 15) ^ (r & 15);
    agp[j] = x + (size_t)(row0 + r) * C_DIM + p * 4;
  }
  const unsigned short* bgp[6];
#pragma unroll
  for (int j = 0; j < 6; ++j) {
    const int s = tid + j * 256;
    const int n = s >> 3, p = (s & 7) ^ (n & 7);
    bgp[j] = wt + (size_t)n * C_DIM + p * 8;
  }

  // fragment LDS byte offsets
  int aoff[2][2];
#pragma unroll
  for (int c = 0; c < 2; ++c)
#pragma unroll
    for (int t = 0; t < 2; ++t)
      aoff[c][t] = (((mh * 16 + m) * 16) + ((c * 8 + 2 * quad + t) ^ m)) << 4;
  int boff[6][2];
#pragma unroll
  for (int j = 0; j < 6; ++j) {
    const int n = (ng + j) * 16 + m;
#pragma unroll
    for (int c = 0; c < 2; ++c)
      boff[j][c] = (n * 8 + ((c * 4 + quad) ^ (n & 7))) << 4;
  }

#define STAGE(buf, kk)                                                       \
  do {                                                                       \
    _Pragma("unroll") for (int j = 0; j < 2; ++j)                            \
        gl_lds16(agp[j] + (kk), abuf[buf], au + (unsigned)(j * 4096));       \
    _Pragma("unroll") for (int j = 0; j < 6; ++j)                            \
        gl_lds16(bgp[j] + (kk), bbuf[buf], au + (unsigned)(j * 4096));       \
  } while (0)

  STAGE(0, 0);
  for (int it = 0; it < 16; ++it) {
    __syncthreads();                     // stage(it) landed (vmcnt drain)
    if (it < 15) STAGE((it + 1) & 1, (it + 1) * 64);
    const unsigned char* aB = abuf[it & 1];
    const unsigned char* bB = bbuf[it & 1];
#pragma unroll
    for (int c = 0; c < 2; ++c) {
      float4 xa = *(const float4*)(aB + aoff[c][0]);
      float4 xb = *(const float4*)(aB + aoff[c][1]);
      s8v a = cvt8(xa, xb);
#pragma unroll
      for (int j = 0; j < 6; ++j) {
        s8v b = *(const s8v*)(bB + boff[j][c]);
        acc[j] = __builtin_amdgcn_mfma_f32_16x16x32_bf16(a, b, acc[j], 0, 0, 0);
      }
    }
  }
#undef STAGE

  // epilogue: C/D layout col=lane&15, row=quad*4+r
  const float qscale = 1.4426950408889634f / 32.0f;  // log2e / sqrt(C)
#pragma unroll
  for (int j = 0; j < 6; ++j) {
    const int nt = ng + j;
    const int mat = nt >> 2, ct = nt & 3;
    const int col = ct * 16 + m;
#pragma unroll
    for (int r = 0; r < 4; ++r) {
      const int row = row0 + mh * 16 + quad * 4 + r;
      const float v = acc[j][r];
      if (mat == 0) {
        qws[row * HS + col] = f2bf(v * qscale);
      } else if (mat == 1) {
        kws[row * HS + col] = f2bf(v);
      } else {
        const int bb = row >> 11, t = row & 2047;
        vtws[(bb * HS + col) * T_SEQ + t] = f2bf(v);
      }
    }
  }
}

// ------------- Kernel B: causal flash attention ------------------------
// grid 1024 x 512 threads, __launch_bounds__(512,2): VGPR cap 256 so the
// full K+V fragment set (64 VGPRs) plus a depth-1 prefetch set stays
// resident — R5-R7's cap of 64 VGPRs serialized loads behind uses.
// XCD pinning: batch = blockIdx.x & 7. qt pairing (j&1 ? 127-(j>>1) :
// j>>1) balances heavy/light blocks in any dispatch window.
union AttnSh {
  unsigned short p[8][16 * 72];   // per-wave P tile, 16 rows x 72 (pad) u16
  float mo[8][16][64];            // per-wave O partials (merge phase)
};

__global__ __launch_bounds__(512, 2) void attn_kernel(
    const unsigned short* __restrict__ qws, const unsigned short* __restrict__ kws,
    const unsigned short* __restrict__ vtws, float* __restrict__ out) {
  __shared__ AttnSh sh;
  __shared__ float ml[8][16];

  const int tid  = threadIdx.x;
  const int wv   = tid >> 6;
  const int lane = tid & 63;
  const int m    = lane & 15;
  const int quad = lane >> 4;
  const int b    = blockIdx.x & 7;                 // XCD-pinned batch
  const int j    = blockIdx.x >> 3;
  const int qt   = (j & 1) ? (127 - (j >> 1)) : (j >> 1);  // balanced pairing
  const int r0   = qt * 16;
  const int gr0  = b * T_SEQ + r0;

  s8v aq0 = *(const s8v*)&qws[(size_t)(gr0 + m) * HS + quad * 8];
  s8v aq1 = *(const s8v*)&qws[(size_t)(gr0 + m) * HS + 32 + quad * 8];

  float li[4] = {0.f, 0.f, 0.f, 0.f};
  f4v o[4];
#pragma unroll
  for (int i = 0; i < 4; ++i) o[i] = (f4v)0.0f;

  const int nst = (r0 + 16 + 63) >> 6;       // causal 64-wide tile bound
  unsigned short* pl = sh.p[wv];
  const int qrow_base = r0 + quad * 4;
  const unsigned short* kbase = kws + (size_t)b * T_SEQ * HS;
  const unsigned short* vbase = vtws + (size_t)b * HS * T_SEQ;

  // depth-1 rotated prefetch of K/V fragments
  s8v kf[4][2], vf[4][2];
  {
    const int s0c = ((wv < nst) ? wv : 0) * 64;
#pragma unroll
    for (int ns = 0; ns < 4; ++ns) {
      const unsigned short* kp = &kbase[(size_t)(s0c + ns * 16 + m) * HS + quad * 8];
      kf[ns][0] = *(const s8v*)kp;
      kf[ns][1] = *(const s8v*)(kp + 32);
      const unsigned short* vp = &vbase[(size_t)(ns * 16 + m) * T_SEQ + s0c + quad * 8];
      vf[ns][0] = *(const s8v*)vp;
      vf[ns][1] = *(const s8v*)(vp + 32);
    }
  }

  for (int st = wv; st < nst; st += 8) {
    const int s0 = st * 64;
    const int sn = ((st + 8 < nst) ? st + 8 : st) * 64;  // clamped prefetch

    // issue next-tile loads first (land during this iteration's compute)
    s8v nkf[4][2], nvf[4][2];
#pragma unroll
    for (int ns = 0; ns < 4; ++ns) {
      const unsigned short* kp = &kbase[(size_t)(sn + ns * 16 + m) * HS + quad * 8];
      nkf[ns][0] = *(const s8v*)kp;
      nkf[ns][1] = *(const s8v*)(kp + 32);
      const unsigned short* vp = &vbase[(size_t)(ns * 16 + m) * T_SEQ + sn + quad * 8];
      nvf[ns][0] = *(const s8v*)vp;
      nvf[ns][1] = *(const s8v*)(vp + 32);
    }

    // S = Q K^T : 4 independent chains of 2 MFMAs
    f4v sacc[4];
#pragma unroll
    for (int ns = 0; ns < 4; ++ns) {
      f4v t = (f4v)0.0f;
      t = __builtin_amdgcn_mfma_f32_16x16x32_bf16(aq0, kf[ns][0], t, 0, 0, 0);
      t = __builtin_amdgcn_mfma_f32_16x16x32_bf16(aq1, kf[ns][1], t, 0, 0, 0);
      sacc[ns] = t;
    }

    // mask + exp2 (no max subtraction: |logit| <~ 1), accumulate l, P->LDS
#pragma unroll
    for (int ns = 0; ns < 4; ++ns) {
      const int scol = s0 + ns * 16 + m;
#pragma unroll
      for (int r = 0; r < 4; ++r) {
        const float p = (scol > qrow_base + r) ? 0.f
                        : __builtin_amdgcn_exp2f(sacc[ns][r]);
        li[r] += p;
        pl[(quad * 4 + r) * 72 + ns * 16 + m] = f2bf(p);
      }
    }

    // O += P V : A-frags from LDS (same-wave RAW; DS pipe in-order)
    s8v ap0 = *(const s8v*)&pl[m * 72 + quad * 8];
    s8v ap1 = *(const s8v*)&pl[m * 72 + 32 + quad * 8];
#pragma unroll
    for (int hn = 0; hn < 4; ++hn) {
      o[hn] = __builtin_amdgcn_mfma_f32_16x16x32_bf16(ap0, vf[hn][0], o[hn], 0, 0, 0);
      o[hn] = __builtin_amdgcn_mfma_f32_16x16x32_bf16(ap1, vf[hn][1], o[hn], 0, 0, 0);
    }

    // rotate prefetch
#pragma unroll
    for (int ns = 0; ns < 4; ++ns) {
      kf[ns][0] = nkf[ns][0]; kf[ns][1] = nkf[ns][1];
      vf[ns][0] = nvf[ns][0]; vf[ns][1] = nvf[ns][1];
    }
  }

#pragma unroll
  for (int r = 0; r < 4; ++r) {
    float s = li[r];
    s += __shfl_xor(s, 1); s += __shfl_xor(s, 2);
    s += __shfl_xor(s, 4); s += __shfl_xor(s, 8);
    li[r] = s;
  }

  __syncthreads();   // all waves done with P regions (union reuse)

#pragma unroll
  for (int hn = 0; hn < 4; ++hn)
#pragma unroll
    for (int r = 0; r < 4; ++r)
      sh.mo[wv][quad * 4 + r][hn * 16 + m] = o[hn][r];
  if (m == 0) {
#pragma unroll
    for (int r = 0; r < 4; ++r) ml[wv][quad * 4 + r] = li[r];
  }
  __syncthreads();

  const int row = tid >> 5, cg = tid & 31;
  float ls = 0.f;
#pragma unroll
  for (int w = 0; w < 8; ++w) ls += ml[w][row];
  const float inv = 1.0f / ls;
  float rx = 0.f, ry = 0.f;
#pragma unroll
  for (int w = 0; w < 8; ++w) {
    float2 v = *(const float2*)&sh.mo[w][row][cg * 2];
    rx += v.x; ry += v.y;
  }
  float2 res; res.x = rx * inv; res.y = ry * inv;
  *(float2*)&out[(size_t)(gr0 + row) * HS + cg * 2] = res;
}

extern "C" void kernel_launch(void* const* d_in, const int* in_sizes, int n_in,
                              void* d_out, int out_size, void* d_ws, size_t ws_size,
                              hipStream_t stream) {
  const float* x  = (const float*)d_in[0];
  const float* Wq = (const float*)d_in[1];
  const float* Wk = (const float*)d_in[2];
  const float* Wv = (const float*)d_in[3];
  float* out = (float*)d_out;

  unsigned short* qws  = (unsigned short*)d_ws;          // 2 MB
  unsigned short* kws  = qws + (size_t)BT * HS;          // 2 MB
  unsigned short* vtws = kws + (size_t)BT * HS;          // 2 MB
  unsigned short* wt   = vtws + (size_t)BT * HS;         // 384 KB

  wt_kernel<<<dim3(48), dim3(256), 0, stream>>>(Wq, Wk, Wv, wt);
  qkv_kernel<<<dim3(BT / 32), dim3(256), 0, stream>>>(x, wt, qws, kws, vtws);
  attn_kernel<<<dim3(1024), dim3(512), 0, stream>>>(qws, kws, vtws, out);
}

// Round 9
// 171.964 us; speedup vs baseline: 1.0500x; 1.0500x over previous
//
#include <hip/hip_runtime.h>
#include <hip/hip_bf16.h>

// Problem: B=8, T=2048, C=1024, HS=64. fp32 in/out.
// d_in: x[8,2048,1024], Wq[1024,64], Wk[1024,64], Wv[1024,64]
// d_out: [8,2048,64] fp32
// Workspace: q bf16 [16384][64] (pre-scaled log2e/32), k bf16 [16384][64],
//            vT bf16 [8][64][2048], Wt bf16 [192][1024]  (~6.4 MB)

#define T_SEQ 2048
#define C_DIM 1024
#define HS 64
#define BT 16384

typedef short s8v __attribute__((ext_vector_type(8)));   // 8 bf16
typedef float f4v __attribute__((ext_vector_type(4)));   // MFMA C/D

__device__ inline unsigned short f2bf(float f) {
  union { float f; unsigned u; } a; a.f = f;
  unsigned r = a.u + 0x7fffu + ((a.u >> 16) & 1u);  // RNE
  return (unsigned short)(r >> 16);
}

// HW-packed f32x2 -> bf16x2 (v_cvt_pk_bf16_f32), 4 ops per 8 elements
__device__ inline s8v cvt8(float4 v0, float4 v1) {
  union { __hip_bfloat162 h; unsigned u; } c0, c1, c2, c3;
  c0.h = __float22bfloat162_rn(make_float2(v0.x, v0.y));
  c1.h = __float22bfloat162_rn(make_float2(v0.z, v0.w));
  c2.h = __float22bfloat162_rn(make_float2(v1.x, v1.y));
  c3.h = __float22bfloat162_rn(make_float2(v1.z, v1.w));
  union { unsigned u[4]; s8v v; } r;
  r.u[0] = c0.u; r.u[1] = c1.u; r.u[2] = c2.u; r.u[3] = c3.u;
  return r.v;
}

// async global->LDS, 16 B/lane. LDS base MUST be wave-uniform (SGPR).
__device__ inline void gl_lds16(const void* g, unsigned char* lds_base,
                                unsigned uniform_byte_off) {
  __builtin_amdgcn_global_load_lds(
      (const __attribute__((address_space(1))) unsigned int*)g,
      (__attribute__((address_space(3))) unsigned int*)(lds_base + uniform_byte_off),
      16, 0, 0);
}

// ------------- Kernel 0: W transpose via LDS (coalesced both ways) -------
__global__ __launch_bounds__(256) void wt_kernel(
    const float* __restrict__ Wq, const float* __restrict__ Wk,
    const float* __restrict__ Wv, unsigned short* __restrict__ wt) {
  __shared__ float tile[64][65];
  const int bid = blockIdx.x;
  const int mat = bid >> 4, kt = bid & 15;
  const float* W = (mat == 0) ? Wq : ((mat == 1) ? Wk : Wv);
  const int t = threadIdx.x;
  const int n = t & 63, kr = t >> 6;
#pragma unroll
  for (int j = 0; j < 16; ++j) {
    const int kl = j * 4 + kr;
    tile[kl][n] = W[(kt * 64 + kl) * HS + n];
  }
  __syncthreads();
  const int n2 = t >> 2, kp = t & 3;
  unsigned int* orow =
      (unsigned int*)(wt + (size_t)(mat * 64 + n2) * C_DIM + kt * 64);
#pragma unroll
  for (int i = 0; i < 8; ++i) {
    const int k0 = kp * 16 + i * 2;
    unsigned int lo = f2bf(tile[k0][n2]);
    unsigned int hi = f2bf(tile[k0 + 1][n2]);
    orow[kp * 8 + i] = lo | (hi << 16);
  }
}

// ------------- Kernel A: QKV projection, hybrid staging ------------------
// 512 blocks x 256 threads. M-tile 32; N = 192; BK = 64; 16 iterations.
// A (x tile): async global_load_lds double-buffer (16 KB LDS total).
// B (weights): direct 16B loads from L2-resident Wt, issued BEFORE the
// barrier each iteration -> the vmcnt(0) drain at the barrier covers
// max(A-stage, B-loads) instead of serializing them. This is the overlap
// the pure-LDS 2-barrier structure can't express (R6 was 64 KB LDS and
// barrier-drain bound at ~38 us).
__global__ __launch_bounds__(256, 4) void qkv_kernel(
    const float* __restrict__ x, const unsigned short* __restrict__ wt,
    unsigned short* __restrict__ qws, unsigned short* __restrict__ kws,
    unsigned short* __restrict__ vtws) {
  __shared__ unsigned char abuf[2][8192];    // 32 rows x 64 fp32 (16 parts)

  const int tid  = threadIdx.x;
  const int wv   = tid >> 6;
  const int lane = tid & 63;
  const int m    = lane & 15;
  const int quad = lane >> 4;
  const int row0 = blockIdx.x * 32;
  const int mh   = wv >> 1;            // wave's m-half (0/1)
  const int ng   = (wv & 1) * 6;       // wave's first n-tile

  f4v acc[6];
#pragma unroll
  for (int j = 0; j < 6; ++j) acc[j] = (f4v)0.0f;

  // wave-uniform LDS slot base (bytes); HW adds lane*16
  const unsigned au = (unsigned)__builtin_amdgcn_readfirstlane(tid & 192) << 4;

  // A staging slot -> global mapping (XOR-swizzled 16B parts within rows)
  const float* agp[2];
#pragma unroll
  for (int j = 0; j < 2; ++j) {
    const int s = tid + j * 256;
    const int r = s >> 4, p = (s & 15) ^ (r & 15);
    agp[j] = x + (size_t)(row0 + r) * C_DIM + p * 4;
  }

  // A fragment LDS byte offsets (2 k-chunks x 2 16B-subloads)
  int aoff[2][2];
#pragma unroll
  for (int c = 0; c < 2; ++c)
#pragma unroll
    for (int t = 0; t < 2; ++t)
      aoff[c][t] = (((mh * 16 + m) * 16) + ((c * 8 + 2 * quad + t) ^ m)) << 4;

  // B global pointers: wave's 6 n-tiles, row n = (ng+j)*16 + m
  const unsigned short* bgp[6];
#pragma unroll
  for (int j = 0; j < 6; ++j)
    bgp[j] = wt + (size_t)((ng + j) * 16 + m) * C_DIM + quad * 8;

#define STAGE_A(buf, kk)                                                     \
  do {                                                                       \
    _Pragma("unroll") for (int j = 0; j < 2; ++j)                            \
        gl_lds16(agp[j] + (kk), abuf[buf], au + (unsigned)(j * 4096));       \
  } while (0)

  STAGE_A(0, 0);
  for (int it = 0; it < 16; ++it) {
    const int kk = it * 64;
    // B fragment loads for THIS iteration (L2-resident; independent of the
    // barrier — they drain concurrently with the A-stage at the barrier)
    s8v bf[6][2];
#pragma unroll
    for (int j = 0; j < 6; ++j) {
      bf[j][0] = *(const s8v*)(bgp[j] + kk);
      bf[j][1] = *(const s8v*)(bgp[j] + kk + 32);
    }
    __syncthreads();                     // A stage(it) + B loads landed
    if (it < 15) STAGE_A((it + 1) & 1, kk + 64);
    const unsigned char* aB = abuf[it & 1];
#pragma unroll
    for (int c = 0; c < 2; ++c) {
      float4 xa = *(const float4*)(aB + aoff[c][0]);
      float4 xb = *(const float4*)(aB + aoff[c][1]);
      s8v a = cvt8(xa, xb);
#pragma unroll
      for (int j = 0; j < 6; ++j)
        acc[j] = __builtin_amdgcn_mfma_f32_16x16x32_bf16(a, bf[j][c], acc[j], 0, 0, 0);
    }
  }
#undef STAGE_A

  // epilogue: C/D layout col=lane&15, row=quad*4+r
  const float qscale = 1.4426950408889634f / 32.0f;  // log2e / sqrt(C)
#pragma unroll
  for (int j = 0; j < 6; ++j) {
    const int nt = ng + j;
    const int mat = nt >> 2, ct = nt & 3;
    const int col = ct * 16 + m;
#pragma unroll
    for (int r = 0; r < 4; ++r) {
      const int row = row0 + mh * 16 + quad * 4 + r;
      const float v = acc[j][r];
      if (mat == 0) {
        qws[row * HS + col] = f2bf(v * qscale);
      } else if (mat == 1) {
        kws[row * HS + col] = f2bf(v);
      } else {
        const int bb = row >> 11, t = row & 2047;
        vtws[(bb * HS + col) * T_SEQ + t] = f2bf(v);
      }
    }
  }
}

// ------------- Kernel B: causal flash attention (R6 revert: 41.4 us) -----
// grid 1024 x 512 threads. XCD pinning: batch = blockIdx.x & 7; LPT
// qt = 127 - (blockIdx.x>>3). 8 waves stride 64-wide s-tiles. No register
// prefetch (compiler flattens it — measured 3x in this session).
union AttnSh {
  unsigned short p[8][16 * 72];   // per-wave P tile, 16 rows x 72 (pad) u16
  float mo[8][16][64];            // per-wave O partials (merge phase)
};

__global__ __launch_bounds__(512) void attn_kernel(
    const unsigned short* __restrict__ qws, const unsigned short* __restrict__ kws,
    const unsigned short* __restrict__ vtws, float* __restrict__ out) {
  __shared__ AttnSh sh;
  __shared__ float ml[8][16];

  const int tid  = threadIdx.x;
  const int wv   = tid >> 6;
  const int lane = tid & 63;
  const int m    = lane & 15;
  const int quad = lane >> 4;
  const int b    = blockIdx.x & 7;                        // XCD-pinned batch
  const int qt   = (T_SEQ / 16 - 1) - (blockIdx.x >> 3);  // LPT
  const int r0   = qt * 16;
  const int gr0  = b * T_SEQ + r0;

  s8v aq0 = *(const s8v*)&qws[(size_t)(gr0 + m) * HS + quad * 8];
  s8v aq1 = *(const s8v*)&qws[(size_t)(gr0 + m) * HS + 32 + quad * 8];

  float li[4] = {0.f, 0.f, 0.f, 0.f};
  f4v o[4];
#pragma unroll
  for (int i = 0; i < 4; ++i) o[i] = (f4v)0.0f;

  const int nst = (r0 + 16 + 63) >> 6;       // causal 64-wide tile bound
  unsigned short* pl = sh.p[wv];
  const int qrow_base = r0 + quad * 4;
  const unsigned short* kbase = kws + (size_t)b * T_SEQ * HS;
  const unsigned short* vbase = vtws + (size_t)b * HS * T_SEQ;

  for (int st = wv; st < nst; st += 8) {
    const int s0 = st * 64;

    s8v kf[4][2];
#pragma unroll
    for (int ns = 0; ns < 4; ++ns) {
      const unsigned short* kp = &kbase[(size_t)(s0 + ns * 16 + m) * HS + quad * 8];
      kf[ns][0] = *(const s8v*)kp;
      kf[ns][1] = *(const s8v*)(kp + 32);
    }
    s8v vf[4][2];
#pragma unroll
    for (int hn = 0; hn < 4; ++hn) {
      const unsigned short* vp = &vbase[(size_t)(hn * 16 + m) * T_SEQ + s0 + quad * 8];
      vf[hn][0] = *(const s8v*)vp;
      vf[hn][1] = *(const s8v*)(vp + 32);
    }

    f4v sacc[4];
#pragma unroll
    for (int ns = 0; ns < 4; ++ns) {
      f4v t = (f4v)0.0f;
      t = __builtin_amdgcn_mfma_f32_16x16x32_bf16(aq0, kf[ns][0], t, 0, 0, 0);
      t = __builtin_amdgcn_mfma_f32_16x16x32_bf16(aq1, kf[ns][1], t, 0, 0, 0);
      sacc[ns] = t;
    }

#pragma unroll
    for (int ns = 0; ns < 4; ++ns) {
      const int scol = s0 + ns * 16 + m;
#pragma unroll
      for (int r = 0; r < 4; ++r) {
        const float p = (scol > qrow_base + r) ? 0.f
                        : __builtin_amdgcn_exp2f(sacc[ns][r]);
        li[r] += p;
        pl[(quad * 4 + r) * 72 + ns * 16 + m] = f2bf(p);
      }
    }

    // O += P V : A-frags from LDS (same-wave RAW; DS pipe in-order)
    s8v ap0 = *(const s8v*)&pl[m * 72 + quad * 8];
    s8v ap1 = *(const s8v*)&pl[m * 72 + 32 + quad * 8];
#pragma unroll
    for (int hn = 0; hn < 4; ++hn) {
      o[hn] = __builtin_amdgcn_mfma_f32_16x16x32_bf16(ap0, vf[hn][0], o[hn], 0, 0, 0);
      o[hn] = __builtin_amdgcn_mfma_f32_16x16x32_bf16(ap1, vf[hn][1], o[hn], 0, 0, 0);
    }
  }

#pragma unroll
  for (int r = 0; r < 4; ++r) {
    float s = li[r];
    s += __shfl_xor(s, 1); s += __shfl_xor(s, 2);
    s += __shfl_xor(s, 4); s += __shfl_xor(s, 8);
    li[r] = s;
  }

  __syncthreads();   // all waves done with P regions (union reuse)

#pragma unroll
  for (int hn = 0; hn < 4; ++hn)
#pragma unroll
    for (int r = 0; r < 4; ++r)
      sh.mo[wv][quad * 4 + r][hn * 16 + m] = o[hn][r];
  if (m == 0) {
#pragma unroll
    for (int r = 0; r < 4; ++r) ml[wv][quad * 4 + r] = li[r];
  }
  __syncthreads();

  const int row = tid >> 5, cg = tid & 31;
  float ls = 0.f;
#pragma unroll
  for (int w = 0; w < 8; ++w) ls += ml[w][row];
  const float inv = 1.0f / ls;
  float rx = 0.f, ry = 0.f;
#pragma unroll
  for (int w = 0; w < 8; ++w) {
    float2 v = *(const float2*)&sh.mo[w][row][cg * 2];
    rx += v.x; ry += v.y;
  }
  float2 res; res.x = rx * inv; res.y = ry * inv;
  *(float2*)&out[(size_t)(gr0 + row) * HS + cg * 2] = res;
}

extern "C" void kernel_launch(void* const* d_in, const int* in_sizes, int n_in,
                              void* d_out, int out_size, void* d_ws, size_t ws_size,
                              hipStream_t stream) {
  const float* x  = (const float*)d_in[0];
  const float* Wq = (const float*)d_in[1];
  const float* Wk = (const float*)d_in[2];
  const float* Wv = (const float*)d_in[3];
  float* out = (float*)d_out;

  unsigned short* qws  = (unsigned short*)d_ws;          // 2 MB
  unsigned short* kws  = qws + (size_t)BT * HS;          // 2 MB
  unsigned short* vtws = kws + (size_t)BT * HS;          // 2 MB
  unsigned short* wt   = vtws + (size_t)BT * HS;         // 384 KB

  wt_kernel<<<dim3(48), dim3(256), 0, stream>>>(Wq, Wk, Wv, wt);
  qkv_kernel<<<dim3(BT / 32), dim3(256), 0, stream>>>(x, wt, qws, kws, vtws);
  attn_kernel<<<dim3(1024), dim3(512), 0, stream>>>(qws, kws, vtws, out);
}

// Round 10
// 158.543 us; speedup vs baseline: 1.1388x; 1.0847x over previous
//
#include <hip/hip_runtime.h>
#include <hip/hip_bf16.h>

// Problem: B=8, T=2048, C=1024, HS=64. fp32 in/out.
// d_in: x[8,2048,1024], Wq[1024,64], Wk[1024,64], Wv[1024,64]
// d_out: [8,2048,64] fp32
// Workspace: q bf16 [16384][64] (pre-scaled log2e/32), k bf16 [16384][64],
//            vT bf16 [8][64][2048], Wt bf16 [192][1024]  (~6.4 MB)

#define T_SEQ 2048
#define C_DIM 1024
#define HS 64
#define BT 16384

typedef short s8v __attribute__((ext_vector_type(8)));   // 8 bf16
typedef float f4v __attribute__((ext_vector_type(4)));   // MFMA C/D

__device__ inline unsigned short f2bf(float f) {
  union { float f; unsigned u; } a; a.f = f;
  unsigned r = a.u + 0x7fffu + ((a.u >> 16) & 1u);  // RNE
  return (unsigned short)(r >> 16);
}

// HW-packed f32x2 -> bf16x2 (v_cvt_pk_bf16_f32)
__device__ inline s8v cvt8(float4 v0, float4 v1) {
  union { __hip_bfloat162 h; unsigned u; } c0, c1, c2, c3;
  c0.h = __float22bfloat162_rn(make_float2(v0.x, v0.y));
  c1.h = __float22bfloat162_rn(make_float2(v0.z, v0.w));
  c2.h = __float22bfloat162_rn(make_float2(v1.x, v1.y));
  c3.h = __float22bfloat162_rn(make_float2(v1.z, v1.w));
  union { unsigned u[4]; s8v v; } r;
  r.u[0] = c0.u; r.u[1] = c1.u; r.u[2] = c2.u; r.u[3] = c3.u;
  return r.v;
}

// async global->LDS, 16 B/lane. LDS base MUST be wave-uniform (SGPR).
__device__ inline void gl_lds16(const void* g, unsigned char* lds_base,
                                unsigned uniform_byte_off) {
  __builtin_amdgcn_global_load_lds(
      (const __attribute__((address_space(1))) unsigned int*)g,
      (__attribute__((address_space(3))) unsigned int*)(lds_base + uniform_byte_off),
      16, 0, 0);
}

// ------------- Kernel 0: W transpose via LDS (coalesced both ways) -------
__global__ __launch_bounds__(256) void wt_kernel(
    const float* __restrict__ Wq, const float* __restrict__ Wk,
    const float* __restrict__ Wv, unsigned short* __restrict__ wt) {
  __shared__ float tile[64][65];
  const int bid = blockIdx.x;
  const int mat = bid >> 4, kt = bid & 15;
  const float* W = (mat == 0) ? Wq : ((mat == 1) ? Wk : Wv);
  const int t = threadIdx.x;
  const int n = t & 63, kr = t >> 6;
#pragma unroll
  for (int j = 0; j < 16; ++j) {
    const int kl = j * 4 + kr;
    tile[kl][n] = W[(kt * 64 + kl) * HS + n];
  }
  __syncthreads();
  const int n2 = t >> 2, kp = t & 3;
  unsigned int* orow =
      (unsigned int*)(wt + (size_t)(mat * 64 + n2) * C_DIM + kt * 64);
#pragma unroll
  for (int i = 0; i < 8; ++i) {
    const int k0 = kp * 16 + i * 2;
    unsigned int lo = f2bf(tile[k0][n2]);
    unsigned int hi = f2bf(tile[k0 + 1][n2]);
    orow[kp * 8 + i] = lo | (hi << 16);
  }
}

// ------------- Kernel A: QKV projection (R7-measured pure-LDS) -----------
// 512 blocks x 256 threads. M-tile 32; N = 192; BK = 64; 16 barriers.
__global__ __launch_bounds__(256) void qkv_kernel(
    const float* __restrict__ x, const unsigned short* __restrict__ wt,
    unsigned short* __restrict__ qws, unsigned short* __restrict__ kws,
    unsigned short* __restrict__ vtws) {
  __shared__ unsigned char abuf[2][8192];    // 32 rows x 64 fp32 (16 parts)
  __shared__ unsigned char bbuf[2][24576];   // 192 rows x 64 bf16 (8 parts)

  const int tid  = threadIdx.x;
  const int wv   = tid >> 6;
  const int lane = tid & 63;
  const int m    = lane & 15;
  const int quad = lane >> 4;
  const int row0 = blockIdx.x * 32;
  const int mh   = wv >> 1;
  const int ng   = (wv & 1) * 6;

  f4v acc[6];
#pragma unroll
  for (int j = 0; j < 6; ++j) acc[j] = (f4v)0.0f;

  const unsigned au = (unsigned)__builtin_amdgcn_readfirstlane(tid & 192) << 4;

  const float* agp[2];
#pragma unroll
  for (int j = 0; j < 2; ++j) {
    const int s = tid + j * 256;
    const int r = s >> 4, p = (s & 15) ^ (r & 15);
    agp[j] = x + (size_t)(row0 + r) * C_DIM + p * 4;
  }
  const unsigned short* bgp[6];
#pragma unroll
  for (int j = 0; j < 6; ++j) {
    const int s = tid + j * 256;
    const int n = s >> 3, p = (s & 7) ^ (n & 7);
    bgp[j] = wt + (size_t)n * C_DIM + p * 8;
  }

  int aoff[2][2];
#pragma unroll
  for (int c = 0; c < 2; ++c)
#pragma unroll
    for (int t = 0; t < 2; ++t)
      aoff[c][t] = (((mh * 16 + m) * 16) + ((c * 8 + 2 * quad + t) ^ m)) << 4;
  int boff[6][2];
#pragma unroll
  for (int j = 0; j < 6; ++j) {
    const int n = (ng + j) * 16 + m;
#pragma unroll
    for (int c = 0; c < 2; ++c)
      boff[j][c] = (n * 8 + ((c * 4 + quad) ^ (n & 7))) << 4;
  }

#define STAGE(buf, kk)                                                       \
  do {                                                                       \
    _Pragma("unroll") for (int j = 0; j < 2; ++j)                            \
        gl_lds16(agp[j] + (kk), abuf[buf], au + (unsigned)(j * 4096));       \
    _Pragma("unroll") for (int j = 0; j < 6; ++j)                            \
        gl_lds16(bgp[j] + (kk), bbuf[buf], au + (unsigned)(j * 4096));       \
  } while (0)

  STAGE(0, 0);
  for (int it = 0; it < 16; ++it) {
    __syncthreads();
    if (it < 15) STAGE((it + 1) & 1, (it + 1) * 64);
    const unsigned char* aB = abuf[it & 1];
    const unsigned char* bB = bbuf[it & 1];
#pragma unroll
    for (int c = 0; c < 2; ++c) {
      float4 xa = *(const float4*)(aB + aoff[c][0]);
      float4 xb = *(const float4*)(aB + aoff[c][1]);
      s8v a = cvt8(xa, xb);
#pragma unroll
      for (int j = 0; j < 6; ++j) {
        s8v b = *(const s8v*)(bB + boff[j][c]);
        acc[j] = __builtin_amdgcn_mfma_f32_16x16x32_bf16(a, b, acc[j], 0, 0, 0);
      }
    }
  }
#undef STAGE

  const float qscale = 1.4426950408889634f / 32.0f;  // log2e / sqrt(C)
#pragma unroll
  for (int j = 0; j < 6; ++j) {
    const int nt = ng + j;
    const int mat = nt >> 2, ct = nt & 3;
    const int col = ct * 16 + m;
#pragma unroll
    for (int r = 0; r < 4; ++r) {
      const int row = row0 + mh * 16 + quad * 4 + r;
      const float v = acc[j][r];
      if (mat == 0) {
        qws[row * HS + col] = f2bf(v * qscale);
      } else if (mat == 1) {
        kws[row * HS + col] = f2bf(v);
      } else {
        const int bb = row >> 11, t = row & 2047;
        vtws[(bb * HS + col) * T_SEQ + t] = f2bf(v);
      }
    }
  }
}

// ------------- Kernel B: flash attention, LDS-shared K/V tiles -----------
// 256 blocks x 512 threads. Block = 64 q-rows of one batch (XCD-pinned
// b = blockIdx.x&7, LPT qt = 31-(blockIdx.x>>3)). 8 waves = 4 q-subtiles
// x 2 s-tile parities. Per s-tile (64 wide): one 16 KB K+V stage via
// global_load_lds (double-buffered); 4 active waves read fragments from
// LDS. Cuts L2 fragment traffic 8x vs per-wave L2 loads (R6..R9 design).
// 16B parts XOR-swizzled by row: frag ds_read_b128 is 2-way (free).
union AttnSh {
  unsigned short p[8][16 * 76];                       // P tiles (19456 B)
  struct { float mo[4][16][64]; float ml[4][16]; } m; // merge (16640 B)
};

__global__ __launch_bounds__(512, 2) void attn_kernel(
    const unsigned short* __restrict__ qws, const unsigned short* __restrict__ kws,
    const unsigned short* __restrict__ vtws, float* __restrict__ out) {
  __shared__ unsigned char kbuf[2][8192];   // K tile: 64 s-rows x 64 h bf16
  __shared__ unsigned char vbuf[2][8192];   // V tile: 64 h-rows x 64 s bf16
  __shared__ AttnSh sh;

  const int tid  = threadIdx.x;
  const int wv   = tid >> 6;
  const int lane = tid & 63;
  const int m    = lane & 15;
  const int quad = lane >> 4;
  const int b    = blockIdx.x & 7;               // XCD-pinned batch
  const int qt   = 31 - (blockIdx.x >> 3);       // 64-row tile, LPT
  const int r0   = qt * 64;
  const int qsub = wv >> 1;                      // wave's 16-row q-subtile
  const int par  = wv & 1;                       // wave's s-tile parity
  const int rw   = r0 + qsub * 16;
  const int gr0  = b * T_SEQ + rw;

  s8v aq0 = *(const s8v*)&qws[(size_t)(gr0 + m) * HS + quad * 8];
  s8v aq1 = *(const s8v*)&qws[(size_t)(gr0 + m) * HS + 32 + quad * 8];

  float li[4] = {0.f, 0.f, 0.f, 0.f};
  f4v o[4];
#pragma unroll
  for (int i = 0; i < 4; ++i) o[i] = (f4v)0.0f;

  const int nst    = qt + 1;                     // s-tiles this block needs
  const int mylast = (rw + 15) >> 6;             // last tile this wave needs
  const int qrow_base = rw + quad * 4;
  unsigned short* pl = sh.p[wv];

  const unsigned short* kbase = kws + (size_t)b * T_SEQ * HS;
  const unsigned short* vbase = vtws + (size_t)b * HS * T_SEQ;

  // staging: thread t -> physical slot t (16B); logical row t>>3,
  // part (t&7)^(row&7). Global stays 128B-coalesced per row.
  const int rt = tid >> 3;
  const int pt = (tid & 7) ^ (rt & 7);
  const unsigned au = (unsigned)__builtin_amdgcn_readfirstlane(tid & 448) << 4;

  // fragment slot byte offsets: logical (row, part c*4+quad) ->
  // slot row*8 + ((c*4+quad)^(row&7)); row low3 = m&7.
  int fo[4][2];
#pragma unroll
  for (int ns = 0; ns < 4; ++ns)
#pragma unroll
    for (int c = 0; c < 2; ++c)
      fo[ns][c] = ((ns * 16 + m) * 8 + ((c * 4 + quad) ^ (m & 7))) << 4;

#define STAGEKV(buf, st)                                                     \
  do {                                                                       \
    const int s0_ = (st) * 64;                                               \
    gl_lds16(kbase + (size_t)(s0_ + rt) * HS + pt * 8, kbuf[buf], au);       \
    gl_lds16(vbase + (size_t)rt * T_SEQ + s0_ + pt * 8, vbuf[buf], au);      \
  } while (0)

  STAGEKV(0, 0);
  for (int st = 0; st < nst; ++st) {
    __syncthreads();                   // stage(st) landed; buf^1 free
    if (st + 1 < nst) STAGEKV((st + 1) & 1, st + 1);
    if ((st & 1) == par && st <= mylast) {
      const unsigned char* kB = kbuf[st & 1];
      const unsigned char* vB = vbuf[st & 1];
      const int s0 = st * 64;

      // S = Q K^T : 4 independent chains of 2 MFMAs
      f4v sacc[4];
#pragma unroll
      for (int ns = 0; ns < 4; ++ns) {
        f4v t = (f4v)0.0f;
        t = __builtin_amdgcn_mfma_f32_16x16x32_bf16(
            aq0, *(const s8v*)(kB + fo[ns][0]), t, 0, 0, 0);
        t = __builtin_amdgcn_mfma_f32_16x16x32_bf16(
            aq1, *(const s8v*)(kB + fo[ns][1]), t, 0, 0, 0);
        sacc[ns] = t;
      }

      // mask + exp2 (no max subtraction: |logit| <~ 1), l accum, P->LDS
#pragma unroll
      for (int ns = 0; ns < 4; ++ns) {
        const int scol = s0 + ns * 16 + m;
#pragma unroll
        for (int r = 0; r < 4; ++r) {
          const float p = (scol > qrow_base + r) ? 0.f
                          : __builtin_amdgcn_exp2f(sacc[ns][r]);
          li[r] += p;
          pl[(quad * 4 + r) * 76 + ns * 16 + m] = f2bf(p);
        }
      }

      // O += P V : A-frags from LDS (same-wave RAW; DS pipe in-order)
      s8v ap0 = *(const s8v*)&pl[m * 76 + quad * 8];
      s8v ap1 = *(const s8v*)&pl[m * 76 + 32 + quad * 8];
#pragma unroll
      for (int hn = 0; hn < 4; ++hn) {
        o[hn] = __builtin_amdgcn_mfma_f32_16x16x32_bf16(
            ap0, *(const s8v*)(vB + fo[hn][0]), o[hn], 0, 0, 0);
        o[hn] = __builtin_amdgcn_mfma_f32_16x16x32_bf16(
            ap1, *(const s8v*)(vB + fo[hn][1]), o[hn], 0, 0, 0);
      }
    }
  }

  // reduce l across the 16 lanes of each q-row group
#pragma unroll
  for (int r = 0; r < 4; ++r) {
    float s = li[r];
    s += __shfl_xor(s, 1); s += __shfl_xor(s, 2);
    s += __shfl_xor(s, 4); s += __shfl_xor(s, 8);
    li[r] = s;
  }

  __syncthreads();   // all waves done with P regions (union reuse)

  // 2-way merge across s-parities: odd wave publishes, even wave combines
  if (par == 1) {
#pragma unroll
    for (int hn = 0; hn < 4; ++hn)
#pragma unroll
      for (int r = 0; r < 4; ++r)
        sh.m.mo[qsub][quad * 4 + r][hn * 16 + m] = o[hn][r];
    if (m == 0) {
#pragma unroll
      for (int r = 0; r < 4; ++r) sh.m.ml[qsub][quad * 4 + r] = li[r];
    }
  }
  __syncthreads();
  if (par == 0) {
#pragma unroll
    for (int r = 0; r < 4; ++r) {
      const int row = quad * 4 + r;
      const float inv = 1.0f / (li[r] + sh.m.ml[qsub][row]);
#pragma unroll
      for (int hn = 0; hn < 4; ++hn) {
        const float v = o[hn][r] + sh.m.mo[qsub][row][hn * 16 + m];
        out[(size_t)(gr0 + row) * HS + hn * 16 + m] = v * inv;
      }
    }
  }
}

extern "C" void kernel_launch(void* const* d_in, const int* in_sizes, int n_in,
                              void* d_out, int out_size, void* d_ws, size_t ws_size,
                              hipStream_t stream) {
  const float* x  = (const float*)d_in[0];
  const float* Wq = (const float*)d_in[1];
  const float* Wk = (const float*)d_in[2];
  const float* Wv = (const float*)d_in[3];
  float* out = (float*)d_out;

  unsigned short* qws  = (unsigned short*)d_ws;          // 2 MB
  unsigned short* kws  = qws + (size_t)BT * HS;          // 2 MB
  unsigned short* vtws = kws + (size_t)BT * HS;          // 2 MB
  unsigned short* wt   = vtws + (size_t)BT * HS;         // 384 KB

  wt_kernel<<<dim3(48), dim3(256), 0, stream>>>(Wq, Wk, Wv, wt);
  qkv_kernel<<<dim3(BT / 32), dim3(256), 0, stream>>>(x, wt, qws, kws, vtws);
  attn_kernel<<<dim3(256), dim3(512), 0, stream>>>(qws, kws, vtws, out);
}

// Round 11
// 158.202 us; speedup vs baseline: 1.1413x; 1.0022x over previous
//
#include <hip/hip_runtime.h>
#include <hip/hip_bf16.h>

// Problem: B=8, T=2048, C=1024, HS=64. fp32 in/out.
// d_in: x[8,2048,1024], Wq[1024,64], Wk[1024,64], Wv[1024,64]
// d_out: [8,2048,64] fp32
// Workspace: q bf16 [16384][64] (pre-scaled log2e/32), k bf16 [16384][64],
//            vT bf16 [8][64][2048], Wt bf16 [192][1024]  (~6.4 MB)

#define T_SEQ 2048
#define C_DIM 1024
#define HS 64
#define BT 16384

typedef short s8v __attribute__((ext_vector_type(8)));   // 8 bf16
typedef float f4v __attribute__((ext_vector_type(4)));   // MFMA C/D

__device__ inline unsigned short f2bf(float f) {
  union { float f; unsigned u; } a; a.f = f;
  unsigned r = a.u + 0x7fffu + ((a.u >> 16) & 1u);  // RNE
  return (unsigned short)(r >> 16);
}

// HW-packed f32x2 -> bf16x2 (v_cvt_pk_bf16_f32)
__device__ inline s8v cvt8(float4 v0, float4 v1) {
  union { __hip_bfloat162 h; unsigned u; } c0, c1, c2, c3;
  c0.h = __float22bfloat162_rn(make_float2(v0.x, v0.y));
  c1.h = __float22bfloat162_rn(make_float2(v0.z, v0.w));
  c2.h = __float22bfloat162_rn(make_float2(v1.x, v1.y));
  c3.h = __float22bfloat162_rn(make_float2(v1.z, v1.w));
  union { unsigned u[4]; s8v v; } r;
  r.u[0] = c0.u; r.u[1] = c1.u; r.u[2] = c2.u; r.u[3] = c3.u;
  return r.v;
}

// async global->LDS, 16 B/lane. LDS base MUST be wave-uniform (SGPR).
__device__ inline void gl_lds16(const void* g, unsigned char* lds_base,
                                unsigned uniform_byte_off) {
  __builtin_amdgcn_global_load_lds(
      (const __attribute__((address_space(1))) unsigned int*)g,
      (__attribute__((address_space(3))) unsigned int*)(lds_base + uniform_byte_off),
      16, 0, 0);
}

// ------------- Kernel 0: W transpose via LDS (coalesced both ways) -------
__global__ __launch_bounds__(256) void wt_kernel(
    const float* __restrict__ Wq, const float* __restrict__ Wk,
    const float* __restrict__ Wv, unsigned short* __restrict__ wt) {
  __shared__ float tile[64][65];
  const int bid = blockIdx.x;
  const int mat = bid >> 4, kt = bid & 15;
  const float* W = (mat == 0) ? Wq : ((mat == 1) ? Wk : Wv);
  const int t = threadIdx.x;
  const int n = t & 63, kr = t >> 6;
#pragma unroll
  for (int j = 0; j < 16; ++j) {
    const int kl = j * 4 + kr;
    tile[kl][n] = W[(kt * 64 + kl) * HS + n];
  }
  __syncthreads();
  const int n2 = t >> 2, kp = t & 3;
  unsigned int* orow =
      (unsigned int*)(wt + (size_t)(mat * 64 + n2) * C_DIM + kt * 64);
#pragma unroll
  for (int i = 0; i < 8; ++i) {
    const int k0 = kp * 16 + i * 2;
    unsigned int lo = f2bf(tile[k0][n2]);
    unsigned int hi = f2bf(tile[k0 + 1][n2]);
    orow[kp * 8 + i] = lo | (hi << 16);
  }
}

// ------------- Kernel A: QKV projection, 4-stage ring + manual barrier ---
// 512 blocks x 256 threads. M-tile 32; N = 192; BK = 32; 32 iterations.
// Ring of 4 stages (16 KB each = A 4 KB + B 12 KB, 64 KB total). Keeps 3
// stages (12 loads/wave) in flight across a RAW s_barrier; drains only the
// oldest stage via s_waitcnt vmcnt(8) — the AITER pattern __syncthreads
// (vmcnt(0)) cannot express. Constant depth via wrapped dummy prefetches.
__global__ __launch_bounds__(256, 2) void qkv_kernel(
    const float* __restrict__ x, const unsigned short* __restrict__ wt,
    unsigned short* __restrict__ qws, unsigned short* __restrict__ kws,
    unsigned short* __restrict__ vtws) {
  __shared__ unsigned char ring[4][16384];   // A @0 (4 KB), B @4096 (12 KB)

  const int tid  = threadIdx.x;
  const int wv   = tid >> 6;
  const int lane = tid & 63;
  const int m    = lane & 15;
  const int quad = lane >> 4;
  const int row0 = blockIdx.x * 32;
  const int mh   = wv >> 1;            // wave's m-half (0/1)
  const int ng   = (wv & 1) * 6;       // wave's first n-tile

  f4v acc[6];
#pragma unroll
  for (int j = 0; j < 6; ++j) acc[j] = (f4v)0.0f;

  const unsigned au = (unsigned)__builtin_amdgcn_readfirstlane(tid & 192) << 4;

  // A: slot = tid -> row tid>>3, 16B part (tid&7)^(row&7)
  const int ar = tid >> 3;
  const int apt = (tid & 7) ^ (ar & 7);
  const float* agp = x + (size_t)(row0 + ar) * C_DIM + apt * 4;
  // B: slot = tid + j*256 -> n s>>2, part (s&3)^(n&3)
  const unsigned short* bgp[3];
#pragma unroll
  for (int j = 0; j < 3; ++j) {
    const int s = tid + j * 256;
    const int n = s >> 2, p = (s & 3) ^ (n & 3);
    bgp[j] = wt + (size_t)n * C_DIM + p * 8;
  }

  // fragment LDS byte offsets (row&7 == m&7, n&3 patterns)
  int aoff[2];
#pragma unroll
  for (int t = 0; t < 2; ++t)
    aoff[t] = (((mh * 16 + m) * 8) + ((2 * quad + t) ^ (m & 7))) << 4;
  int boff[6];
#pragma unroll
  for (int j = 0; j < 6; ++j) {
    const int n = (ng + j) * 16 + m;
    boff[j] = (n * 4 + (quad ^ (n & 3))) << 4;
  }

#define STAGE(slot, kk)                                                      \
  do {                                                                       \
    gl_lds16(agp + (kk), ring[slot], au);                                    \
    _Pragma("unroll") for (int j = 0; j < 3; ++j)                            \
        gl_lds16(bgp[j] + (kk), ring[slot] + 4096,                           \
                 au + (unsigned)(j * 4096));                                 \
  } while (0)

  STAGE(0, 0);
  STAGE(1, 32);
  STAGE(2, 64);
  for (int it = 0; it < 32; ++it) {
    // drain ONLY the oldest in-flight stage (4 loads/wave), then barrier.
    asm volatile("s_waitcnt vmcnt(8)\n\ts_barrier" ::: "memory");
    // keep depth constant: wrapped dummy prefetch past the end (valid addrs,
    // lands in a slot whose stage was consumed before this barrier).
    STAGE((it + 3) & 3, ((it + 3) & 31) * 32);
    const unsigned char* aB = ring[it & 3];
    const unsigned char* bB = ring[it & 3] + 4096;
    float4 xa = *(const float4*)(aB + aoff[0]);
    float4 xb = *(const float4*)(aB + aoff[1]);
    s8v a = cvt8(xa, xb);
#pragma unroll
    for (int j = 0; j < 6; ++j) {
      s8v b = *(const s8v*)(bB + boff[j]);
      acc[j] = __builtin_amdgcn_mfma_f32_16x16x32_bf16(a, b, acc[j], 0, 0, 0);
    }
  }
#undef STAGE
  // drain remaining dummy prefetches before LDS goes away / epilogue
  asm volatile("s_waitcnt vmcnt(0)" ::: "memory");

  // epilogue: C/D layout col=lane&15, row=quad*4+r
  const float qscale = 1.4426950408889634f / 32.0f;  // log2e / sqrt(C)
#pragma unroll
  for (int j = 0; j < 6; ++j) {
    const int nt = ng + j;
    const int mat = nt >> 2, ct = nt & 3;
    const int col = ct * 16 + m;
#pragma unroll
    for (int r = 0; r < 4; ++r) {
      const int row = row0 + mh * 16 + quad * 4 + r;
      const float v = acc[j][r];
      if (mat == 0) {
        qws[row * HS + col] = f2bf(v * qscale);
      } else if (mat == 1) {
        kws[row * HS + col] = f2bf(v);
      } else {
        const int bb = row >> 11, t = row & 2047;
        vtws[(bb * HS + col) * T_SEQ + t] = f2bf(v);
      }
    }
  }
}

// ------------- Kernel B: flash attention, LDS K/V tiles, 2 blocks/CU -----
// 512 blocks x 256 threads. Block = 32 q-rows of one batch (XCD-pinned
// b = bid&7, LPT qt = 63-(bid>>3)); 2 blocks/CU -> barrier drains overlap
// across blocks and short blocks backfill (fixes R9's 1-block/CU serial).
// 4 waves = 2 q-subtiles x 2 s-parities. Per 64-wide s-tile: 16 KB K+V
// staged via global_load_lds dbuf. Diagonal-only masking (wave-uniform
// branch); l accumulated by an extra ones-column MFMA (o4).
union AttnSh {
  unsigned short p[4][16 * 76];                       // P tiles (9728 B)
  struct { float mo[2][16][64]; float ml[2][16]; } m; // merge (8320 B)
};

__global__ __launch_bounds__(256, 2) void attn_kernel(
    const unsigned short* __restrict__ qws, const unsigned short* __restrict__ kws,
    const unsigned short* __restrict__ vtws, float* __restrict__ out) {
  __shared__ unsigned char kbuf[2][8192];   // K tile: 64 s-rows x 64 h bf16
  __shared__ unsigned char vbuf[2][8192];   // V tile: 64 h-rows x 64 s bf16
  __shared__ AttnSh sh;

  const int tid  = threadIdx.x;
  const int wv   = tid >> 6;
  const int lane = tid & 63;
  const int m    = lane & 15;
  const int quad = lane >> 4;
  const int b    = blockIdx.x & 7;               // XCD-pinned batch
  const int qt   = 63 - (blockIdx.x >> 3);       // 32-row q-tile, LPT
  const int qsub = wv >> 1;                      // wave's 16-row q-subtile
  const int par  = wv & 1;                       // wave's s-tile parity
  const int rw   = qt * 32 + qsub * 16;
  const int gr0  = b * T_SEQ + rw;

  s8v aq0 = *(const s8v*)&qws[(size_t)(gr0 + m) * HS + quad * 8];
  s8v aq1 = *(const s8v*)&qws[(size_t)(gr0 + m) * HS + 32 + quad * 8];

  s8v ones;
#pragma unroll
  for (int i = 0; i < 8; ++i) ones[i] = (short)0x3F80;   // bf16 1.0

  f4v o[4], o4;
#pragma unroll
  for (int i = 0; i < 4; ++i) o[i] = (f4v)0.0f;
  o4 = (f4v)0.0f;

  const int nst = (32 * qt + 95) >> 6;           // s-tiles this block scans
  const int t_d = (rw + 15) >> 6;                // wave's diagonal tile
  const int qrow_base = rw + quad * 4;
  unsigned short* pl = sh.p[wv];

  const unsigned short* kbase = kws + (size_t)b * T_SEQ * HS;
  const unsigned short* vbase = vtws + (size_t)b * HS * T_SEQ;

  // staging: 2 calls/buffer; slot s = tid + j*256 -> row s>>3,
  // part (s&7)^(row&7). au per call = wave slot base (HW adds lane*16).
  int srow[2], spart[2];
#pragma unroll
  for (int j = 0; j < 2; ++j) {
    const int s = tid + j * 256;
    srow[j] = s >> 3;
    spart[j] = (s & 7) ^ (srow[j] & 7);
  }
  const unsigned au = (unsigned)__builtin_amdgcn_readfirstlane(tid & 192) << 4;

  // fragment slot byte offsets (row low3 = m&7)
  int fo[4][2];
#pragma unroll
  for (int ns = 0; ns < 4; ++ns)
#pragma unroll
    for (int c = 0; c < 2; ++c)
      fo[ns][c] = ((ns * 16 + m) * 8 + ((c * 4 + quad) ^ (m & 7))) << 4;

#define STAGEKV(buf, st)                                                     \
  do {                                                                       \
    const int s0_ = (st) * 64;                                               \
    _Pragma("unroll") for (int j = 0; j < 2; ++j) {                          \
      gl_lds16(kbase + (size_t)(s0_ + srow[j]) * HS + spart[j] * 8,          \
               kbuf[buf], au + (unsigned)(j * 4096));                        \
      gl_lds16(vbase + (size_t)srow[j] * T_SEQ + s0_ + spart[j] * 8,         \
               vbuf[buf], au + (unsigned)(j * 4096));                        \
    }                                                                        \
  } while (0)

  STAGEKV(0, 0);
  for (int st = 0; st < nst; ++st) {
    __syncthreads();                   // stage(st) landed; buf^1 free
    if (st + 1 < nst) STAGEKV((st + 1) & 1, st + 1);
    if ((st & 1) == par && st <= t_d) {
      const unsigned char* kB = kbuf[st & 1];
      const unsigned char* vB = vbuf[st & 1];
      const int s0 = st * 64;

      f4v sacc[4];
#pragma unroll
      for (int ns = 0; ns < 4; ++ns) {
        f4v t = (f4v)0.0f;
        t = __builtin_amdgcn_mfma_f32_16x16x32_bf16(
            aq0, *(const s8v*)(kB + fo[ns][0]), t, 0, 0, 0);
        t = __builtin_amdgcn_mfma_f32_16x16x32_bf16(
            aq1, *(const s8v*)(kB + fo[ns][1]), t, 0, 0, 0);
        sacc[ns] = t;
      }

      if (st < t_d) {
        // full tile: no masking VALU at all
#pragma unroll
        for (int ns = 0; ns < 4; ++ns)
#pragma unroll
          for (int r = 0; r < 4; ++r)
            pl[(quad * 4 + r) * 76 + ns * 16 + m] =
                f2bf(__builtin_amdgcn_exp2f(sacc[ns][r]));
      } else {
        // diagonal tile: causal mask
#pragma unroll
        for (int ns = 0; ns < 4; ++ns) {
          const int scol = s0 + ns * 16 + m;
#pragma unroll
          for (int r = 0; r < 4; ++r) {
            const float p = (scol > qrow_base + r) ? 0.f
                            : __builtin_amdgcn_exp2f(sacc[ns][r]);
            pl[(quad * 4 + r) * 76 + ns * 16 + m] = f2bf(p);
          }
        }
      }

      // O += P V, l += P·1 (ones-column MFMA; same-wave LDS RAW, in-order)
      s8v ap0 = *(const s8v*)&pl[m * 76 + quad * 8];
      s8v ap1 = *(const s8v*)&pl[m * 76 + 32 + quad * 8];
#pragma unroll
      for (int hn = 0; hn < 4; ++hn) {
        o[hn] = __builtin_amdgcn_mfma_f32_16x16x32_bf16(
            ap0, *(const s8v*)(vB + fo[hn][0]), o[hn], 0, 0, 0);
        o[hn] = __builtin_amdgcn_mfma_f32_16x16x32_bf16(
            ap1, *(const s8v*)(vB + fo[hn][1]), o[hn], 0, 0, 0);
      }
      o4 = __builtin_amdgcn_mfma_f32_16x16x32_bf16(ap0, ones, o4, 0, 0, 0);
      o4 = __builtin_amdgcn_mfma_f32_16x16x32_bf16(ap1, ones, o4, 0, 0, 0);
    }
  }

  __syncthreads();   // all waves done with P regions (union reuse)

  // 2-way merge across s-parities: odd wave publishes, even combines
  if (par == 1) {
#pragma unroll
    for (int hn = 0; hn < 4; ++hn)
#pragma unroll
      for (int r = 0; r < 4; ++r)
        sh.m.mo[qsub][quad * 4 + r][hn * 16 + m] = o[hn][r];
    if (m == 0) {
#pragma unroll
      for (int r = 0; r < 4; ++r) sh.m.ml[qsub][quad * 4 + r] = o4[r];
    }
  }
  __syncthreads();
  if (par == 0) {
#pragma unroll
    for (int r = 0; r < 4; ++r) {
      const int row = quad * 4 + r;
      const float inv = 1.0f / (o4[r] + sh.m.ml[qsub][row]);
#pragma unroll
      for (int hn = 0; hn < 4; ++hn) {
        const float v = o[hn][r] + sh.m.mo[qsub][row][hn * 16 + m];
        out[(size_t)(gr0 + row) * HS + hn * 16 + m] = v * inv;
      }
    }
  }
}

extern "C" void kernel_launch(void* const* d_in, const int* in_sizes, int n_in,
                              void* d_out, int out_size, void* d_ws, size_t ws_size,
                              hipStream_t stream) {
  const float* x  = (const float*)d_in[0];
  const float* Wq = (const float*)d_in[1];
  const float* Wk = (const float*)d_in[2];
  const float* Wv = (const float*)d_in[3];
  float* out = (float*)d_out;

  unsigned short* qws  = (unsigned short*)d_ws;          // 2 MB
  unsigned short* kws  = qws + (size_t)BT * HS;          // 2 MB
  unsigned short* vtws = kws + (size_t)BT * HS;          // 2 MB
  unsigned short* wt   = vtws + (size_t)BT * HS;         // 384 KB

  wt_kernel<<<dim3(48), dim3(256), 0, stream>>>(Wq, Wk, Wv, wt);
  qkv_kernel<<<dim3(BT / 32), dim3(256), 0, stream>>>(x, wt, qws, kws, vtws);
  attn_kernel<<<dim3(512), dim3(256), 0, stream>>>(qws, kws, vtws, out);
}